// Round 1
// baseline (915.795 us; speedup 1.0000x reference)
//
#include <hip/hip_runtime.h>
#include <math.h>

typedef unsigned short u16;
typedef __bf16 bf16x8 __attribute__((ext_vector_type(8)));
typedef float f32x4 __attribute__((ext_vector_type(4)));

#define T_TOK 4096
#define DIMD 2048
#define HIDD 1024
#define NEXP 16
#define RMAX 10240
#define MAXBLK 96
#define BM 128
#define BN 128
#define BK 32
#define LDK 40   // BK + 8 pad, keeps 16B alignment for b128 LDS ops

__device__ __forceinline__ u16 f2b(float f) {
  unsigned u = __builtin_bit_cast(unsigned, f);
  unsigned r = (u + 0x7FFFu + ((u >> 16) & 1u)) >> 16;  // RNE
  return (u16)r;
}

// ---------------- small kernels ----------------

__global__ void k_init(int* perm, int* cnt, int* fill) {
  int i = blockIdx.x * blockDim.x + threadIdx.x;
  if (i < RMAX) perm[i] = -1;
  if (i < NEXP) { cnt[i] = 0; fill[i] = 0; }
}

__global__ void k_cvt(const float* __restrict__ x, u16* __restrict__ xb) {
  const int i = blockIdx.x * blockDim.x + threadIdx.x;
  const float4 v = ((const float4*)x)[i];
  union { u16 u[4]; unsigned long long q; } t;
  t.u[0] = f2b(v.x); t.u[1] = f2b(v.y); t.u[2] = f2b(v.z); t.u[3] = f2b(v.w);
  ((unsigned long long*)xb)[i] = t.q;
}

// gating: fp32 logits = x @ gate_w, softmax, top-2, partial prob sums
__global__ __launch_bounds__(256)
void k_gate(const float* __restrict__ x, const float* __restrict__ gw,
            int* __restrict__ top2i, float* __restrict__ top2w,
            int* __restrict__ cnt, float* __restrict__ partial) {
  const int e = threadIdx.x & 15;
  const int tt = threadIdx.x >> 4;
  const int t = blockIdx.x * 16 + tt;
  const float* xp = x + (size_t)t * DIMD;
  float acc = 0.f;
#pragma unroll 8
  for (int k = 0; k < DIMD; ++k) acc = fmaf(xp[k], gw[k * NEXP + e], acc);
  __shared__ float lg[16][17];
  __shared__ float pr[16][17];
  lg[tt][e] = acc;
  __syncthreads();
  if (e == 0) {
    float l[16];
    float mx = -1e30f;
    for (int j = 0; j < 16; ++j) { l[j] = lg[tt][j]; mx = fmaxf(mx, l[j]); }
    float s = 0.f;
    for (int j = 0; j < 16; ++j) { l[j] = expf(l[j] - mx); s += l[j]; }
    const float inv = 1.f / s;
    float p1 = -1.f, p2 = -1.f; int i1 = 0, i2 = 0;
    for (int j = 0; j < 16; ++j) {
      const float p = l[j] * inv;
      pr[tt][j] = p;
      if (p > p1) { p2 = p1; i2 = i1; p1 = p; i1 = j; }
      else if (p > p2) { p2 = p; i2 = j; }
    }
    const float wsum = p1 + p2;
    top2i[t * 2 + 0] = i1;
    top2i[t * 2 + 1] = i2;
    top2w[t * 2 + 0] = p1 / wsum;
    top2w[t * 2 + 1] = p2 / wsum;
    atomicAdd(&cnt[i1], 1);
    atomicAdd(&cnt[i2], 1);
  }
  __syncthreads();
  if (tt == 0) {
    float s = 0.f;
    for (int j = 0; j < 16; ++j) s += pr[j][e];
    partial[blockIdx.x * 16 + e] = s;
  }
}

__global__ __launch_bounds__(256)
void k_aux(const float* __restrict__ partial, float* __restrict__ auxOut) {
  __shared__ float s[16][17];
  const int e = threadIdx.x & 15, c = threadIdx.x >> 4;
  float a = 0.f;
  for (int b = c; b < 256; b += 16) a += partial[b * 16 + e];
  s[c][e] = a;
  __syncthreads();
  if (threadIdx.x == 0) {
    float aux = 0.f;
    for (int j = 0; j < 16; ++j) {
      float tot = 0.f;
      for (int cc = 0; cc < 16; ++cc) tot += s[cc][j];
      const float m = tot / (float)T_TOK;
      aux += m * m;
    }
    auxOut[0] = aux * (float)NEXP;
  }
}

// padded per-expert offsets + row-block table (single thread; 16 experts)
__global__ void k_off(const int* __restrict__ cnt, int* __restrict__ offs,
                      int* __restrict__ tbl_e, int* __restrict__ tbl_r0,
                      int* __restrict__ nblk) {
  if (threadIdx.x != 0 || blockIdx.x != 0) return;
  int o = 0, nb = 0;
  for (int e = 0; e < NEXP; ++e) {
    offs[e] = o;
    const int b = (cnt[e] + BM - 1) / BM;
    for (int i = 0; i < b; ++i) { tbl_e[nb] = e; tbl_r0[nb] = o + i * BM; ++nb; }
    o += b * BM;
  }
  offs[NEXP] = o;
  nblk[0] = nb;
}

__global__ void k_fill(const int* __restrict__ top2i, const float* __restrict__ top2w,
                       const int* __restrict__ offs, int* __restrict__ fill,
                       int* __restrict__ perm, float* __restrict__ wrow) {
  const int id = blockIdx.x * blockDim.x + threadIdx.x;
  if (id >= T_TOK * 2) return;
  const int e = top2i[id];
  const int pos = atomicAdd(&fill[e], 1);
  const int r = offs[e] + pos;
  perm[r] = id >> 1;
  wrow[r] = top2w[id];
}

// ---------------- GEMM ----------------
// MODE 0: shared up   : A=xb[4096,2048] bf16, B=sw1[z] fp32 [2048,1024], silu->bf16 into hbS cols z*1024+..
// MODE 1: shared down : A=hbS[4096,2048] bf16, B=sw2 cat [2048,2048] fp32, plain fp32 store to d_out
// MODE 2: routed up   : A-rows gathered via perm, B=w1[e] fp32 [2048,1024], silu->bf16 into hbR
// MODE 3: routed down : A=hbR rows direct, B=w2[e] fp32 [1024,2048], weighted atomicAdd scatter to d_out
template<int MODE>
__global__ __launch_bounds__(256)
void k_gemm(const u16* __restrict__ A, const float* __restrict__ Bg,
            void* __restrict__ Outp,
            const int* __restrict__ perm, const float* __restrict__ wrow,
            const int* __restrict__ tbl_e, const int* __restrict__ tbl_r0,
            const int* __restrict__ nblk,
            int K, int lda, int ldb) {
  __shared__ u16 As[BM * LDK];
  __shared__ u16 Bs[BN * LDK];
  __shared__ int rowIdxS[BM];

  const int bx = blockIdx.x, by = blockIdx.y;
  int expert = 0;
  int r0;
  if (MODE == 2 || MODE == 3) {
    if (bx >= *nblk) return;
    expert = tbl_e[bx];
    r0 = tbl_r0[bx];
  } else {
    r0 = bx * BM;
    if (MODE == 0) expert = blockIdx.z;
  }
  const float* B = Bg + (size_t)expert * (size_t)K * (size_t)ldb;

  const int tid = threadIdx.x;
  if (tid < BM) {
    int r = r0 + tid;
    int rowi = r;
    if (MODE == 2) { int p = perm[r]; rowi = (p < 0) ? 0 : p; }  // pads read token 0 (discarded)
    rowIdxS[tid] = rowi;
  }
  __syncthreads();

  f32x4 acc[4][4];
#pragma unroll
  for (int i = 0; i < 4; ++i)
#pragma unroll
    for (int j = 0; j < 4; ++j) {
      acc[i][j][0] = 0.f; acc[i][j][1] = 0.f; acc[i][j][2] = 0.f; acc[i][j][3] = 0.f;
    }

  const int n0 = by * BN;
  // A staging: thread -> rows (tid>>2, +64), k-quarter (tid&3)*8, 16B each
  const int aRow = tid >> 2;
  const int aQ = (tid & 3) * 8;
  // B staging: thread -> col (tid&127), k-octet base (tid>>7)*8 (+16 on 2nd iter)
  const int bNN = tid & 127;
  const int bK0 = (tid >> 7) * 8;

  const int lane = tid & 63;
  const int wv = tid >> 6;
  const int wr = (wv >> 1) * 64;   // wave's 64x64 quadrant
  const int wc = (wv & 1) * 64;
  const int lm = lane & 15;
  const int lq = lane >> 4;

  const u16* aRd = &As[(wr + lm) * LDK + lq * 8];
  const u16* bRd = &Bs[(wc + lm) * LDK + lq * 8];
  const u16* arow0 = A + (size_t)rowIdxS[aRow] * lda + aQ;
  const u16* arow1 = A + (size_t)rowIdxS[aRow + 64] * lda + aQ;

  for (int k0 = 0; k0 < K; k0 += BK) {
    // stage A (bf16 global -> LDS [m][k], stride 40)
    *(int4*)&As[aRow * LDK + aQ] = *(const int4*)(arow0 + k0);
    *(int4*)&As[(aRow + 64) * LDK + aQ] = *(const int4*)(arow1 + k0);
    // stage B (fp32 global, coalesced along n; inline cvt; LDS [n][k])
#pragma unroll
    for (int it = 0; it < 2; ++it) {
      const int kk = bK0 + it * 16;
      const float* g = B + (size_t)(k0 + kk) * ldb + n0 + bNN;
      union { u16 u[8]; int4 v; } tmp;
#pragma unroll
      for (int j = 0; j < 8; ++j) tmp.u[j] = f2b(g[(size_t)j * ldb]);
      *(int4*)&Bs[bNN * LDK + kk] = tmp.v;
    }
    __syncthreads();
    bf16x8 af[4], bq[4];
#pragma unroll
    for (int i = 0; i < 4; ++i) af[i] = *(const bf16x8*)(aRd + i * 16 * LDK);
#pragma unroll
    for (int j = 0; j < 4; ++j) bq[j] = *(const bf16x8*)(bRd + j * 16 * LDK);
#pragma unroll
    for (int i = 0; i < 4; ++i)
#pragma unroll
      for (int j = 0; j < 4; ++j)
        acc[i][j] = __builtin_amdgcn_mfma_f32_16x16x32_bf16(af[i], bq[j], acc[i][j], 0, 0, 0);
    __syncthreads();
  }

  u16* outB16 = (u16*)Outp;
  float* outF = (float*)Outp;
#pragma unroll
  for (int i = 0; i < 4; ++i) {
    const int lr0 = wr + i * 16 + lq * 4;   // C/D layout: row=(lane>>4)*4+r, col=lane&15
#pragma unroll
    for (int j = 0; j < 4; ++j) {
      const int gc = n0 + wc + j * 16 + lm;
#pragma unroll
      for (int r = 0; r < 4; ++r) {
        const float v = acc[i][j][r];
        const int lr = lr0 + r;
        if (MODE == 0) {
          const float s = v / (1.f + expf(-v));
          outB16[(size_t)(r0 + lr) * DIMD + expert * HIDD + gc] = f2b(s);
        } else if (MODE == 2) {
          const float s = v / (1.f + expf(-v));
          outB16[(size_t)(r0 + lr) * HIDD + gc] = f2b(s);
        } else if (MODE == 1) {
          outF[(size_t)(r0 + lr) * DIMD + gc] = v;
        } else {
          const int rr = r0 + lr;
          const int t = perm[rr];
          if (t >= 0) atomicAdd(&outF[(size_t)t * DIMD + gc], wrow[rr] * v);
        }
      }
    }
  }
}

// ---------------- launch ----------------

extern "C" void kernel_launch(void* const* d_in, const int* in_sizes, int n_in,
                              void* d_out, int out_size, void* d_ws, size_t ws_size,
                              hipStream_t stream) {
  const float* x   = (const float*)d_in[0];
  const float* gw  = (const float*)d_in[1];
  const float* sw1 = (const float*)d_in[2];
  const float* sw2 = (const float*)d_in[3];
  const float* w1  = (const float*)d_in[4];
  const float* w2  = (const float*)d_in[5];
  float* out = (float*)d_out;

  char* ws = (char*)d_ws;
  u16* xb  = (u16*)(ws);                              // 16 MB bf16 x
  u16* hbS = (u16*)(ws + (size_t)(16 << 20));         // 16 MB shared h (2 experts concat)
  u16* hbR = (u16*)(ws + (size_t)(32 << 20));         // 20 MB routed h (padded rows)
  char* p  = ws + (size_t)(52 << 20);
  int*   top2i   = (int*)p;    p += T_TOK * 2 * 4;
  float* top2w   = (float*)p;  p += T_TOK * 2 * 4;
  int*   perm    = (int*)p;    p += RMAX * 4;
  float* wrow    = (float*)p;  p += RMAX * 4;
  int*   cnt     = (int*)p;    p += 16 * 4;
  int*   fill    = (int*)p;    p += 16 * 4;
  int*   offs    = (int*)p;    p += 32 * 4;
  int*   tbl_e   = (int*)p;    p += MAXBLK * 4;
  int*   tbl_r0  = (int*)p;    p += MAXBLK * 4;
  int*   nblk    = (int*)p;    p += 16 * 4;
  float* partial = (float*)p;  p += 256 * 16 * 4;

  k_init<<<(RMAX + 255) / 256, 256, 0, stream>>>(perm, cnt, fill);
  k_cvt<<<(T_TOK * DIMD / 4) / 256, 256, 0, stream>>>(x, xb);
  k_gate<<<T_TOK / 16, 256, 0, stream>>>(x, gw, top2i, top2w, cnt, partial);
  k_off<<<1, 64, 0, stream>>>(cnt, offs, tbl_e, tbl_r0, nblk);
  k_fill<<<(T_TOK * 2 + 255) / 256, 256, 0, stream>>>(top2i, top2w, offs, fill, perm, wrow);
  k_aux<<<1, 256, 0, stream>>>(partial, out + (size_t)T_TOK * DIMD);

  // shared up (both shared experts via grid.z)
  k_gemm<0><<<dim3(32, 8, 2), 256, 0, stream>>>(xb, sw1, hbS,
      nullptr, nullptr, nullptr, nullptr, nullptr, 2048, 2048, 1024);
  // shared down (plain store initializes d_out)
  k_gemm<1><<<dim3(32, 16, 1), 256, 0, stream>>>(hbS, sw2, out,
      nullptr, nullptr, nullptr, nullptr, nullptr, 2048, 2048, 2048);
  // routed up (gather)
  k_gemm<2><<<dim3(80, 8, 1), 256, 0, stream>>>(xb, w1, hbR,
      perm, nullptr, tbl_e, tbl_r0, nblk, 2048, 2048, 1024);
  // routed down (weighted atomic scatter)
  k_gemm<3><<<dim3(80, 16, 1), 256, 0, stream>>>(hbR, w2, out,
      perm, wrow, tbl_e, tbl_r0, nblk, 1024, 1024, 2048);
}

// Round 2
// 858.301 us; speedup vs baseline: 1.0670x; 1.0670x over previous
//
#include <hip/hip_runtime.h>
#include <math.h>

typedef unsigned short u16;
typedef __bf16 bf16x8 __attribute__((ext_vector_type(8)));
typedef float f32x4 __attribute__((ext_vector_type(4)));

#define T_TOK 4096
#define DIMD 2048
#define HIDD 1024
#define NEXP 16
#define RMAX 10240
#define MAXBLK 96
#define BM 128
#define BN 128
#define BK 32

__device__ __forceinline__ u16 f2b(float f) {
  unsigned u = __builtin_bit_cast(unsigned, f);
  unsigned r = (u + 0x7FFFu + ((u >> 16) & 1u)) >> 16;  // RNE
  return (u16)r;
}

__device__ __forceinline__ void gld16(const void* g, void* l) {
  __builtin_amdgcn_global_load_lds(
      (const __attribute__((address_space(1))) void*)g,
      (__attribute__((address_space(3))) void*)l, 16, 0, 0);
}

// ---------------- small kernels ----------------

__global__ void k_init(int* perm, int* cnt, int* fill) {
  int i = blockIdx.x * blockDim.x + threadIdx.x;
  if (i < RMAX) perm[i] = -1;
  if (i < NEXP) { cnt[i] = 0; fill[i] = 0; }
}

__global__ void k_cvt(const float* __restrict__ x, u16* __restrict__ xb) {
  const int i = blockIdx.x * blockDim.x + threadIdx.x;
  const float4 v = ((const float4*)x)[i];
  union { u16 u[4]; unsigned long long q; } t;
  t.u[0] = f2b(v.x); t.u[1] = f2b(v.y); t.u[2] = f2b(v.z); t.u[3] = f2b(v.w);
  ((unsigned long long*)xb)[i] = t.q;
}

// transpose+convert: W fp32 [E][K][N] -> Wt bf16 rows of n: Wt[e-part][n][k]
__global__ __launch_bounds__(256)
void k_tr(const float* __restrict__ W, u16* __restrict__ Wt,
          int K, int N, long estride, int ld_out) {
  __shared__ float t[64][65];
  const int e = blockIdx.z;
  const float* Win = W + (size_t)e * (size_t)K * (size_t)N;
  u16* Wo = Wt + (size_t)e * (size_t)estride;
  const int n0 = blockIdx.x * 64, k0 = blockIdx.y * 64;
  const int r = threadIdx.x >> 4;
  const int c = (threadIdx.x & 15) * 4;
#pragma unroll
  for (int p = 0; p < 4; ++p) {
    const int kk = p * 16 + r;
    const float4 v = *(const float4*)&Win[(size_t)(k0 + kk) * N + n0 + c];
    t[kk][c] = v.x; t[kk][c + 1] = v.y; t[kk][c + 2] = v.z; t[kk][c + 3] = v.w;
  }
  __syncthreads();
#pragma unroll
  for (int p = 0; p < 4; ++p) {
    const int nn = p * 16 + r;
    ushort4 o;
    o.x = f2b(t[c + 0][nn]); o.y = f2b(t[c + 1][nn]);
    o.z = f2b(t[c + 2][nn]); o.w = f2b(t[c + 3][nn]);
    *(ushort4*)&Wo[(size_t)(n0 + nn) * ld_out + k0 + c] = o;
  }
}

// gating: fp32 logits = x @ gate_w, softmax, top-2, partial prob sums
__global__ __launch_bounds__(256)
void k_gate(const float* __restrict__ x, const float* __restrict__ gw,
            int* __restrict__ top2i, float* __restrict__ top2w,
            int* __restrict__ cnt, float* __restrict__ partial) {
  const int e = threadIdx.x & 15;
  const int tt = threadIdx.x >> 4;
  const int t = blockIdx.x * 16 + tt;
  const float* xp = x + (size_t)t * DIMD;
  float acc = 0.f;
#pragma unroll 8
  for (int k = 0; k < DIMD; ++k) acc = fmaf(xp[k], gw[k * NEXP + e], acc);
  __shared__ float lg[16][17];
  __shared__ float pr[16][17];
  lg[tt][e] = acc;
  __syncthreads();
  if (e == 0) {
    float l[16];
    float mx = -1e30f;
    for (int j = 0; j < 16; ++j) { l[j] = lg[tt][j]; mx = fmaxf(mx, l[j]); }
    float s = 0.f;
    for (int j = 0; j < 16; ++j) { l[j] = expf(l[j] - mx); s += l[j]; }
    const float inv = 1.f / s;
    float p1 = -1.f, p2 = -1.f; int i1 = 0, i2 = 0;
    for (int j = 0; j < 16; ++j) {
      const float p = l[j] * inv;
      pr[tt][j] = p;
      if (p > p1) { p2 = p1; i2 = i1; p1 = p; i1 = j; }
      else if (p > p2) { p2 = p; i2 = j; }
    }
    const float wsum = p1 + p2;
    top2i[t * 2 + 0] = i1;
    top2i[t * 2 + 1] = i2;
    top2w[t * 2 + 0] = p1 / wsum;
    top2w[t * 2 + 1] = p2 / wsum;
    atomicAdd(&cnt[i1], 1);
    atomicAdd(&cnt[i2], 1);
  }
  __syncthreads();
  if (tt == 0) {
    float s = 0.f;
    for (int j = 0; j < 16; ++j) s += pr[j][e];
    partial[blockIdx.x * 16 + e] = s;
  }
}

__global__ __launch_bounds__(256)
void k_aux(const float* __restrict__ partial, float* __restrict__ auxOut) {
  __shared__ float s[16][17];
  const int e = threadIdx.x & 15, c = threadIdx.x >> 4;
  float a = 0.f;
  for (int b = c; b < 256; b += 16) a += partial[b * 16 + e];
  s[c][e] = a;
  __syncthreads();
  if (threadIdx.x == 0) {
    float aux = 0.f;
    for (int j = 0; j < 16; ++j) {
      float tot = 0.f;
      for (int cc = 0; cc < 16; ++cc) tot += s[cc][j];
      const float m = tot / (float)T_TOK;
      aux += m * m;
    }
    auxOut[0] = aux * (float)NEXP;
  }
}

__global__ void k_off(const int* __restrict__ cnt, int* __restrict__ offs,
                      int* __restrict__ tbl_e, int* __restrict__ tbl_r0,
                      int* __restrict__ nblk) {
  if (threadIdx.x != 0 || blockIdx.x != 0) return;
  int o = 0, nb = 0;
  for (int e = 0; e < NEXP; ++e) {
    offs[e] = o;
    const int b = (cnt[e] + BM - 1) / BM;
    for (int i = 0; i < b; ++i) { tbl_e[nb] = e; tbl_r0[nb] = o + i * BM; ++nb; }
    o += b * BM;
  }
  offs[NEXP] = o;
  nblk[0] = nb;
}

__global__ void k_fill(const int* __restrict__ top2i, const float* __restrict__ top2w,
                       const int* __restrict__ offs, int* __restrict__ fill,
                       int* __restrict__ perm, float* __restrict__ wrow) {
  const int id = blockIdx.x * blockDim.x + threadIdx.x;
  if (id >= T_TOK * 2) return;
  const int e = top2i[id];
  const int pos = atomicAdd(&fill[e], 1);
  const int r = offs[e] + pos;
  perm[r] = id >> 1;
  wrow[r] = top2w[id];
}

// ---------------- GEMM ----------------
// A bf16 [M][lda], Bt bf16 n-major [n][ldb]. All staging via global_load_lds 16B.
// MODE 0: shared up   : silu->bf16 into hbS cols expert*1024+gc
// MODE 1: shared down : plain fp32 store to d_out
// MODE 2: routed up   : A rows gathered via perm, silu->bf16 into hbR
// MODE 3: routed down : weighted fp32 atomicAdd scatter to d_out
template<int MODE>
__global__ __launch_bounds__(256)
void k_gemm(const u16* __restrict__ A, const u16* __restrict__ Bt,
            void* __restrict__ Outp,
            const int* __restrict__ perm, const float* __restrict__ wrow,
            const int* __restrict__ tbl_e, const int* __restrict__ tbl_r0,
            const int* __restrict__ nblk,
            int K, int lda, int ldb, size_t bstride) {
  __shared__ u16 As[BM * BK];
  __shared__ u16 Bs[BN * BK];

  const int bx = blockIdx.x, by = blockIdx.y;
  int expert = 0, r0;
  if (MODE == 2 || MODE == 3) {
    if (bx >= *nblk) return;
    expert = tbl_e[bx];
    r0 = tbl_r0[bx];
  } else {
    r0 = bx * BM;
    if (MODE == 0) expert = blockIdx.z;
  }
  const u16* B = Bt + (size_t)expert * bstride;

  const int tid = threadIdx.x;
  const int w = tid >> 6, lane = tid & 63;
  const int lr = lane >> 2;        // 0..15: row within 16-row segment
  const int lk = (lane & 3) * 8;   // k-offset (elements)

  int ra0 = r0 + w * 32 + lr, ra1 = ra0 + 16;
  if (MODE == 2) {
    const int p0 = perm[ra0]; ra0 = (p0 < 0) ? 0 : p0;
    const int p1 = perm[ra1]; ra1 = (p1 < 0) ? 0 : p1;
  }
  const int n0 = by * BN;
  const u16* ap0 = A + (size_t)ra0 * lda + lk;
  const u16* ap1 = A + (size_t)ra1 * lda + lk;
  const u16* bp0 = B + (size_t)(n0 + w * 32 + lr) * ldb + lk;
  const u16* bp1 = bp0 + (size_t)16 * ldb;
  u16* lA0 = &As[w * 1024];
  u16* lA1 = &As[w * 1024 + 512];
  u16* lB0 = &Bs[w * 1024];
  u16* lB1 = &Bs[w * 1024 + 512];

  f32x4 acc[4][4];
#pragma unroll
  for (int i = 0; i < 4; ++i)
#pragma unroll
    for (int j = 0; j < 4; ++j) {
      acc[i][j][0] = 0.f; acc[i][j][1] = 0.f; acc[i][j][2] = 0.f; acc[i][j][3] = 0.f;
    }

  const int wr = (w >> 1) * 64, wc = (w & 1) * 64;
  const int lm = lane & 15, lq = lane >> 4;
  const u16* aRd = &As[(wr + lm) * BK + lq * 8];
  const u16* bRd = &Bs[(wc + lm) * BK + lq * 8];

  for (int k0 = 0; k0 < K; k0 += BK) {
    gld16(ap0 + k0, lA0);
    gld16(ap1 + k0, lA1);
    gld16(bp0 + k0, lB0);
    gld16(bp1 + k0, lB1);
    __syncthreads();
    bf16x8 af[4], bq[4];
#pragma unroll
    for (int i = 0; i < 4; ++i) af[i] = *(const bf16x8*)(aRd + i * 16 * BK);
#pragma unroll
    for (int j = 0; j < 4; ++j) bq[j] = *(const bf16x8*)(bRd + j * 16 * BK);
#pragma unroll
    for (int i = 0; i < 4; ++i)
#pragma unroll
      for (int j = 0; j < 4; ++j)
        acc[i][j] = __builtin_amdgcn_mfma_f32_16x16x32_bf16(af[i], bq[j], acc[i][j], 0, 0, 0);
    __syncthreads();
  }

  u16* outB16 = (u16*)Outp;
  float* outF = (float*)Outp;
#pragma unroll
  for (int i = 0; i < 4; ++i) {
    const int lr0 = wr + i * 16 + lq * 4;   // C/D: row=(lane>>4)*4+r, col=lane&15
#pragma unroll
    for (int j = 0; j < 4; ++j) {
      const int gc = n0 + wc + j * 16 + lm;
#pragma unroll
      for (int r = 0; r < 4; ++r) {
        const float v = acc[i][j][r];
        const int lrow = lr0 + r;
        if (MODE == 0) {
          const float s = v / (1.f + expf(-v));
          outB16[(size_t)(r0 + lrow) * DIMD + expert * HIDD + gc] = f2b(s);
        } else if (MODE == 2) {
          const float s = v / (1.f + expf(-v));
          outB16[(size_t)(r0 + lrow) * HIDD + gc] = f2b(s);
        } else if (MODE == 1) {
          outF[(size_t)(r0 + lrow) * DIMD + gc] = v;
        } else {
          const int rr = r0 + lrow;
          const int t = perm[rr];
          if (t >= 0) atomicAdd(&outF[(size_t)t * DIMD + gc], wrow[rr] * v);
        }
      }
    }
  }
}

// ---------------- launch ----------------

extern "C" void kernel_launch(void* const* d_in, const int* in_sizes, int n_in,
                              void* d_out, int out_size, void* d_ws, size_t ws_size,
                              hipStream_t stream) {
  const float* x   = (const float*)d_in[0];
  const float* gw  = (const float*)d_in[1];
  const float* sw1 = (const float*)d_in[2];
  const float* sw2 = (const float*)d_in[3];
  const float* w1  = (const float*)d_in[4];
  const float* w2  = (const float*)d_in[5];
  float* out = (float*)d_out;

  char* ws = (char*)d_ws;
  u16* xb    = (u16*)(ws);                         // 16 MB
  u16* hbS   = (u16*)(ws + (size_t)( 16 << 20));   // 16 MB
  u16* hbR   = (u16*)(ws + (size_t)( 32 << 20));   // 20 MB
  u16* sw1t  = (u16*)(ws + (size_t)( 52 << 20));   //  8 MB  [2][1024][2048]
  u16* sw2ct = (u16*)(ws + (size_t)( 60 << 20));   //  8 MB  [2048][2*1024] concat
  u16* w1t   = (u16*)(ws + (size_t)( 68 << 20));   // 64 MB  [16][1024][2048]
  u16* w2t   = (u16*)(ws + (size_t)(132 << 20));   // 64 MB  [16][2048][1024]
  char* p = ws + (size_t)(196 << 20);
  int*   top2i   = (int*)p;    p += T_TOK * 2 * 4;
  float* top2w   = (float*)p;  p += T_TOK * 2 * 4;
  int*   perm    = (int*)p;    p += RMAX * 4;
  float* wrow    = (float*)p;  p += RMAX * 4;
  int*   cnt     = (int*)p;    p += 16 * 4;
  int*   fill    = (int*)p;    p += 16 * 4;
  int*   offs    = (int*)p;    p += 32 * 4;
  int*   tbl_e   = (int*)p;    p += MAXBLK * 4;
  int*   tbl_r0  = (int*)p;    p += MAXBLK * 4;
  int*   nblk    = (int*)p;    p += 16 * 4;
  float* partial = (float*)p;  p += 256 * 16 * 4;

  k_init<<<(RMAX + 255) / 256, 256, 0, stream>>>(perm, cnt, fill);
  k_cvt<<<(T_TOK * DIMD / 4) / 256, 256, 0, stream>>>(x, xb);
  k_gate<<<T_TOK / 16, 256, 0, stream>>>(x, gw, top2i, top2w, cnt, partial);
  k_off<<<1, 64, 0, stream>>>(cnt, offs, tbl_e, tbl_r0, nblk);
  k_fill<<<(T_TOK * 2 + 255) / 256, 256, 0, stream>>>(top2i, top2w, offs, fill, perm, wrow);
  k_aux<<<1, 256, 0, stream>>>(partial, out + (size_t)T_TOK * DIMD);

  // weight transposes (fp32 [K][N] -> bf16 [n][k])
  k_tr<<<dim3(1024 / 64, 2048 / 64,  2), 256, 0, stream>>>(sw1, sw1t, 2048, 1024, 1024l * 2048, 2048);
  k_tr<<<dim3(2048 / 64, 1024 / 64,  2), 256, 0, stream>>>(sw2, sw2ct, 1024, 2048, 1024, 2048);
  k_tr<<<dim3(1024 / 64, 2048 / 64, 16), 256, 0, stream>>>(w1, w1t, 2048, 1024, 1024l * 2048, 2048);
  k_tr<<<dim3(2048 / 64, 1024 / 64, 16), 256, 0, stream>>>(w2, w2t, 1024, 2048, 2048l * 1024, 1024);

  // shared up (both shared experts via grid.z)
  k_gemm<0><<<dim3(32, 8, 2), 256, 0, stream>>>(xb, sw1t, hbS,
      nullptr, nullptr, nullptr, nullptr, nullptr, 2048, 2048, 2048, (size_t)1024 * 2048);
  // shared down (plain store initializes d_out)
  k_gemm<1><<<dim3(32, 16, 1), 256, 0, stream>>>(hbS, sw2ct, out,
      nullptr, nullptr, nullptr, nullptr, nullptr, 2048, 2048, 2048, 0);
  // routed up (gather)
  k_gemm<2><<<dim3(80, 8, 1), 256, 0, stream>>>(xb, w1t, hbR,
      perm, nullptr, tbl_e, tbl_r0, nblk, 2048, 2048, 2048, (size_t)1024 * 2048);
  // routed down (weighted atomic scatter)
  k_gemm<3><<<dim3(80, 16, 1), 256, 0, stream>>>(hbR, w2t, out,
      perm, wrow, tbl_e, tbl_r0, nblk, 1024, 1024, 1024, (size_t)2048 * 1024);
}